// Round 5
// baseline (310.919 us; speedup 1.0000x reference)
//
#include <hip/hip_runtime.h>
#include <math.h>

#define NB 4
#define GH 64
#define GW 64
#define DM 128
#define MW 256
#define NF 10
#define NPTS 65536
#define ENCD 42
#define MT 64          // points per block
#define TPB 256
#define LDK 264        // act row stride in f16

typedef _Float16 f16x8 __attribute__((ext_vector_type(8)));
typedef __fp16 h16x2 __attribute__((ext_vector_type(2)));
typedef float f32x4 __attribute__((ext_vector_type(4)));
typedef float f32x16 __attribute__((ext_vector_type(16)));

// d_ws: [0,8192) film fp32 (4x512); [8192,...) packed f16 weights.
// Main layers, 32x32x16 B-frag: unit = (ksg*8 + ntile)*64 + lane, 8 halves each.
// ksg: layer0 ks 0..11 (K padded 192), layer1 12..27, layer2 28..43, layer3 44..59.
#define KS0 0
#define KS1 12
#define KS2 28
#define KS3 44
#define KS_TOTAL 60
#define NUNIT_MAIN (KS_TOTAL * 8 * 64)    // 30720 units
#define NUNIT_OUT (8 * 64)                // w_out: 16x16x32 frags, 8 kt
#define OUT_OFF ((size_t)NUNIT_MAIN * 8)

__device__ __forceinline__ float gelu_fast(float v) {
  // v * sigmoid(2*sqrt(2/pi)*(v+0.044715 v^3)) via exp2+rcp
  const float t = v * v;
  const float w = fmaf(-0.10294324f, t, -2.3022082f);   // -2*log2e*c0*(1, 0.044715)
  const float e = __builtin_amdgcn_exp2f(v * w);
  return v * __builtin_amdgcn_rcpf(1.0f + e);
}

__device__ __forceinline__ float tanh_fast(float v) {
  const float e = __builtin_amdgcn_exp2f(2.8853900818f * v);  // e^(2v)
  return 1.0f - 2.0f * __builtin_amdgcn_rcpf(1.0f + e);
}

// Fused prep: blocks [0,122) pack weights; blocks [122,126) compute film.
__global__ void prep_kernel(const float* __restrict__ w0, const float* __restrict__ w1,
                            const float* __restrict__ w2, const float* __restrict__ w3,
                            const float* __restrict__ wo,
                            const float* __restrict__ ctx, const float* __restrict__ wf,
                            const float* __restrict__ bf,
                            _Float16* __restrict__ wp, float* __restrict__ filmout) {
  if (blockIdx.x >= 122) {
    const int b = blockIdx.x - 122;
#pragma unroll
    for (int h = 0; h < 2; ++h) {
      const int j = threadIdx.x + h * 256;
      float acc = bf[j];
      for (int k = 0; k < DM; ++k)
        acc = fmaf(ctx[b * DM + k], wf[k * 512 + j], acc);
      filmout[b * 512 + j] = acc;
    }
    return;
  }
  const int u = blockIdx.x * 256 + threadIdx.x;
  const int lane = u & 63;
  if (u < NUNIT_MAIN) {
    const int v = u >> 6;
    const int nt8 = v & 7;       // n-tile of 32
    const int ksg = v >> 3;      // 0..59
    const float* w; int ksl, K;
    if (ksg < KS1)      { w = w0; ksl = ksg - KS0; K = 170; }
    else if (ksg < KS2) { w = w1; ksl = ksg - KS1; K = 256; }
    else if (ksg < KS3) { w = w2; ksl = ksg - KS2; K = 256; }
    else                { w = w3; ksl = ksg - KS3; K = 256; }
    const int n = nt8 * 32 + (lane & 31);
    const int kbase = ksl * 16 + (lane >> 5) * 8;
    _Float16* dst = wp + (size_t)u * 8;
#pragma unroll
    for (int j = 0; j < 8; ++j) {
      const int k = kbase + j;
      dst[j] = (_Float16)((k < K) ? w[k * MW + n] : 0.0f);
    }
  } else if (u < NUNIT_MAIN + NUNIT_OUT) {
    // w_out (256 x 3) -> 16x16x32 B-frag, N padded to 16
    const int kt = (u - NUNIT_MAIN) >> 6;
    const int col = lane & 15;
    const int kbase = kt * 32 + (lane >> 4) * 8;
    _Float16* dst = wp + (size_t)u * 8;
#pragma unroll
    for (int j = 0; j < 8; ++j)
      dst[j] = (_Float16)((col < 3) ? wo[(kbase + j) * 3 + col] : 0.0f);
  }
}

__global__ __launch_bounds__(TPB, 4) void decoder_kernel(
    const float* __restrict__ grid, const float* __restrict__ coords,
    const float* __restrict__ b0, const float* __restrict__ b1,
    const float* __restrict__ b2, const float* __restrict__ b3,
    const float* __restrict__ bo,
    const float* __restrict__ film, const _Float16* __restrict__ wpack,
    float* __restrict__ out) {
  __shared__ _Float16 act[MT * LDK];   // 33792 B
  __shared__ float4 cco4[MT];          // 1024 B

  const int tid = threadIdx.x;
  const int lane = tid & 63;
  const int wc = tid >> 6;             // wave id
  const int wr = wc >> 1;              // row half (32 rows)
  const int wn = wc & 1;               // col half (128 cols)
  const int b = blockIdx.x >> 10;
  const int n0 = (blockIdx.x & 1023) * MT;

  // ---- per-point bilinear setup ----
  if (tid < MT) {
    const float x = coords[(size_t)(n0 + tid) * 2 + 0];
    const float y = coords[(size_t)(n0 + tid) * 2 + 1];
    const float cr = (x + 1.0f) * 0.5f * 63.0f;
    const float cc = (y + 1.0f) * 0.5f * 63.0f;
    const float r0f = floorf(cr), q0f = floorf(cc);
    const int r0 = min(max((int)r0f, 0), GH - 1);
    const int q0 = min(max((int)q0f, 0), GW - 1);
    float4 v;
    v.x = __int_as_float(r0);
    v.y = __int_as_float(q0);
    v.z = cr - r0f;
    v.w = cc - q0f;
    cco4[tid] = v;
  }

  // ---- positional encoding (hw sin/cos, revolutions) + zero-pad 170..191 ----
  {
    const int p = tid & 63;
    const int j = tid >> 6;
    const float x = coords[(size_t)(n0 + p) * 2 + 0];
    const float y = coords[(size_t)(n0 + p) * 2 + 1];
    _Float16* row = act + p * LDK;
    if (j == 0) { row[0] = (_Float16)x; row[1] = (_Float16)y; }
    if (j == 1) {
      for (int c = ENCD + DM; c < ENCD + DM + 22; ++c) row[c] = (_Float16)0.0f;
    }
    for (int i = j; i < NF; i += 4) {
      const float sc = 0.5f * (float)(1 << i);   // x*pi*2^i rad == x*2^(i-1) rev
      const float rx = x * sc, ry = y * sc;
      const float fx = rx - floorf(rx);
      const float fy = ry - floorf(ry);
      row[2 + 4 * i + 0] = (_Float16)__builtin_amdgcn_sinf(fx);
      row[2 + 4 * i + 1] = (_Float16)__builtin_amdgcn_sinf(fy);
      row[2 + 4 * i + 2] = (_Float16)__builtin_amdgcn_cosf(fx);
      row[2 + 4 * i + 3] = (_Float16)__builtin_amdgcn_cosf(fy);
    }
  }
  __syncthreads();

  // ---- bilinear sampling, 4 channels/iter ----
  {
    const float* gb = grid + (size_t)b * (GH * GW * DM);
#pragma unroll
    for (int it = 0; it < (MT * DM / 4) / TPB; ++it) {  // 8 iters
      const int idx = it * TPB + tid;
      const int p = idx >> 5;
      const int c = (idx & 31) * 4;
      const float4 cc4 = cco4[p];
      const int r0 = __float_as_int(cc4.x);
      const int q0 = __float_as_int(cc4.y);
      const float frr = cc4.z, frc = cc4.w;
      const int r1 = min(r0 + 1, GH - 1), q1 = min(q0 + 1, GW - 1);
      const float4 v00 = *(const float4*)(gb + (size_t)(r0 * GW + q0) * DM + c);
      const float4 v01 = *(const float4*)(gb + (size_t)(r0 * GW + q1) * DM + c);
      const float4 v10 = *(const float4*)(gb + (size_t)(r1 * GW + q0) * DM + c);
      const float4 v11 = *(const float4*)(gb + (size_t)(r1 * GW + q1) * DM + c);
      float4 vt, vb, vv;
      vt.x = fmaf(v01.x - v00.x, frc, v00.x);
      vt.y = fmaf(v01.y - v00.y, frc, v00.y);
      vt.z = fmaf(v01.z - v00.z, frc, v00.z);
      vt.w = fmaf(v01.w - v00.w, frc, v00.w);
      vb.x = fmaf(v11.x - v10.x, frc, v10.x);
      vb.y = fmaf(v11.y - v10.y, frc, v10.y);
      vb.z = fmaf(v11.z - v10.z, frc, v10.z);
      vb.w = fmaf(v11.w - v10.w, frc, v10.w);
      vv.x = fmaf(vb.x - vt.x, frr, vt.x);
      vv.y = fmaf(vb.y - vt.y, frr, vt.y);
      vv.z = fmaf(vb.z - vt.z, frr, vt.z);
      vv.w = fmaf(vb.w - vt.w, frr, vt.w);
      const h16x2 lo = __builtin_amdgcn_cvt_pkrtz(vv.x, vv.y);
      const h16x2 hi = __builtin_amdgcn_cvt_pkrtz(vv.z, vv.w);
      *(h16x2*)(act + p * LDK + ENCD + c) = lo;
      *(h16x2*)(act + p * LDK + ENCD + c + 2) = hi;
    }
  }

  // ---- FiLM params for this wave's 4 column tiles ----
  float g1[4], cb0[4];
#pragma unroll
  for (int nt = 0; nt < 4; ++nt) {
    const int col = wn * 128 + nt * 32 + (lane & 31);
    g1[nt] = film[b * 512 + col] + 1.0f;
    cb0[nt] = film[b * 512 + MW + col];
  }
  __syncthreads();

  const int arow = wr * 32 + (lane & 31);      // A row for 32x32 frags
  const int kq32 = (lane >> 5) * 8;            // K octet within ks slab

  // ---- fused MLP layers (32x32x16 MFMA; wave = 32 rows x 128 cols) ----
  auto run_layer = [&](const _Float16* __restrict__ wl,
                       const float* __restrict__ bl, const int Ks) {
    f32x16 acc[4];
#pragma unroll
    for (int nt = 0; nt < 4; ++nt)
#pragma unroll
      for (int r = 0; r < 16; ++r) acc[nt][r] = 0.f;

    float cb[4];
#pragma unroll
    for (int nt = 0; nt < 4; ++nt)
      cb[nt] = fmaf(bl[wn * 128 + nt * 32 + (lane & 31)], g1[nt], cb0[nt]);

#pragma unroll 2
    for (int ks = 0; ks < Ks; ++ks) {
      f16x8 bfr[4];
#pragma unroll
      for (int nt = 0; nt < 4; ++nt)
        bfr[nt] = *(const f16x8*)(wl + ((size_t)((ks * 8 + wn * 4 + nt) * 64 + lane)) * 8);
      const f16x8 afr = *(const f16x8*)(act + arow * LDK + ks * 16 + kq32);
#pragma unroll
      for (int nt = 0; nt < 4; ++nt)
        acc[nt] = __builtin_amdgcn_mfma_f32_32x32x16_f16(afr, bfr[nt], acc[nt], 0, 0, 0);
    }
    __syncthreads();  // all waves done reading act
    // epilogue: C/D 32x32: col=lane&31, row=(r&3)+8*(r>>2)+4*(lane>>5)
#pragma unroll
    for (int nt = 0; nt < 4; ++nt) {
      const int col = wn * 128 + nt * 32 + (lane & 31);
#pragma unroll
      for (int r = 0; r < 16; ++r) {
        const int row = wr * 32 + (r & 3) + 8 * (r >> 2) + 4 * (lane >> 5);
        const float v = fmaf(acc[nt][r], g1[nt], cb[nt]);
        act[row * LDK + col] = (_Float16)gelu_fast(v);
      }
    }
    __syncthreads();
  };

  run_layer(wpack + (size_t)KS0 * 8 * 64 * 8, b0, 12);
  run_layer(wpack + (size_t)KS1 * 8 * 64 * 8, b1, 16);
  run_layer(wpack + (size_t)KS2 * 8 * 64 * 8, b2, 16);
  run_layer(wpack + (size_t)KS3 * 8 * 64 * 8, b3, 16);

  // ---- output layer via 16x16x32 MFMA (N padded to 16) ----
  {
    f32x4 oacc = (f32x4){0.f, 0.f, 0.f, 0.f};
    const _Float16* wob = wpack + OUT_OFF;
    const int arow16 = lane & 15;
    const int kq16 = (lane >> 4) * 8;
#pragma unroll
    for (int kt = 0; kt < 8; ++kt) {
      const f16x8 bfr = *(const f16x8*)(wob + (size_t)(kt * 64 + lane) * 8);
      const f16x8 afr = *(const f16x8*)(act + (wc * 16 + arow16) * LDK + kt * 32 + kq16);
      oacc = __builtin_amdgcn_mfma_f32_16x16x32_f16(afr, bfr, oacc, 0, 0, 0);
    }
    const int col = lane & 15;
    if (col < 3) {
      const float bv = bo[col];
      const int rowb = wc * 16 + (lane >> 4) * 4;
#pragma unroll
      for (int r = 0; r < 4; ++r)
        out[((size_t)b * NPTS + n0 + rowb + r) * 3 + col] = tanh_fast(oacc[r] + bv);
    }
  }
}

extern "C" void kernel_launch(void* const* d_in, const int* in_sizes, int n_in,
                              void* d_out, int out_size, void* d_ws, size_t ws_size,
                              hipStream_t stream) {
  const float* grid   = (const float*)d_in[0];
  const float* ctx    = (const float*)d_in[1];
  const float* coords = (const float*)d_in[2];
  const float* w0 = (const float*)d_in[3];
  const float* b0 = (const float*)d_in[4];
  const float* w1 = (const float*)d_in[5];
  const float* b1 = (const float*)d_in[6];
  const float* w2 = (const float*)d_in[7];
  const float* b2 = (const float*)d_in[8];
  const float* w3 = (const float*)d_in[9];
  const float* b3 = (const float*)d_in[10];
  const float* wf = (const float*)d_in[11];
  const float* bf = (const float*)d_in[12];
  const float* wo = (const float*)d_in[13];
  const float* bo = (const float*)d_in[14];
  float* out = (float*)d_out;

  float* filmbuf = (float*)d_ws;
  _Float16* wpack = (_Float16*)((char*)d_ws + 8192);

  hipLaunchKernelGGL(prep_kernel, dim3(126), dim3(256), 0, stream,
                     w0, w1, w2, w3, wo, ctx, wf, bf, wpack, filmbuf);
  hipLaunchKernelGGL(decoder_kernel, dim3(NB * (NPTS / MT)), dim3(TPB), 0, stream,
                     grid, coords, b0, b1, b2, b3, bo, filmbuf, wpack, out);
}

// Round 6
// 290.323 us; speedup vs baseline: 1.0709x; 1.0709x over previous
//
#include <hip/hip_runtime.h>
#include <math.h>

#define NB 4
#define GH 64
#define GW 64
#define DM 128
#define MW 256
#define NF 10
#define NPTS 65536
#define ENCD 42
#define MT 64          // points per block
#define TPB 256
#define LDK 264        // act row stride in f16

typedef _Float16 f16x8 __attribute__((ext_vector_type(8)));
typedef __fp16 h16x2 __attribute__((ext_vector_type(2)));
typedef float f32x4 __attribute__((ext_vector_type(4)));

// d_ws: [0,8192) film fp32 (4x512); [8192,...) packed f16 weights.
// 16x16x32 B-frags: unit = (ktg*16 + nt)*64 + lane, 8 halves each.
// ktg: layer0 kt 0..5 (K pad 192), layer1 6..13, layer2 14..21, layer3 22..29.
#define KTU 8192       // halves per K=32 slab (16 ntiles * 64 * 8)
#define KT0 0
#define KT1 6
#define KT2 14
#define KT3 22
#define KT_TOTAL 30
#define NUNIT_MAIN (KT_TOTAL * 16 * 64)   // 30720 units
#define NUNIT_OUT (8 * 64)                // w_out 16x16x32 frags, 8 kt
#define OUT_OFF ((size_t)NUNIT_MAIN * 8)

__device__ __forceinline__ float gelu_fast(float v) {
  // v * sigmoid(2*sqrt(2/pi)*(v+0.044715 v^3)) via exp2+rcp
  const float t = v * v;
  const float w = fmaf(-0.10294324f, t, -2.3022082f);   // -2*log2e*c0*(1, 0.044715)
  const float e = __builtin_amdgcn_exp2f(v * w);
  return v * __builtin_amdgcn_rcpf(1.0f + e);
}

__device__ __forceinline__ float tanh_fast(float v) {
  const float e = __builtin_amdgcn_exp2f(2.8853900818f * v);  // e^(2v)
  return 1.0f - 2.0f * __builtin_amdgcn_rcpf(1.0f + e);
}

// Fused prep: blocks [0,122) pack weights; blocks [122,126) compute film.
// 122*256 = 31232 = NUNIT_MAIN + NUNIT_OUT exactly.
__global__ void prep_kernel(const float* __restrict__ w0, const float* __restrict__ w1,
                            const float* __restrict__ w2, const float* __restrict__ w3,
                            const float* __restrict__ wo,
                            const float* __restrict__ ctx, const float* __restrict__ wf,
                            const float* __restrict__ bf,
                            _Float16* __restrict__ wp, float* __restrict__ filmout) {
  if (blockIdx.x >= 122) {
    const int b = blockIdx.x - 122;
#pragma unroll
    for (int h = 0; h < 2; ++h) {
      const int j = threadIdx.x + h * 256;
      float acc = bf[j];
      for (int k = 0; k < DM; ++k)
        acc = fmaf(ctx[b * DM + k], wf[k * 512 + j], acc);
      filmout[b * 512 + j] = acc;
    }
    return;
  }
  const int u = blockIdx.x * 256 + threadIdx.x;
  const int lane = u & 63;
  if (u < NUNIT_MAIN) {
    const int v = u >> 6;
    const int nt = v & 15;
    const int ktg = v >> 4;
    const float* w; int ktl, K;
    if (ktg < KT1)      { w = w0; ktl = ktg - KT0; K = 170; }
    else if (ktg < KT2) { w = w1; ktl = ktg - KT1; K = 256; }
    else if (ktg < KT3) { w = w2; ktl = ktg - KT2; K = 256; }
    else                { w = w3; ktl = ktg - KT3; K = 256; }
    const int n = nt * 16 + (lane & 15);
    const int kbase = ktl * 32 + (lane >> 4) * 8;
    _Float16* dst = wp + (size_t)u * 8;
#pragma unroll
    for (int j = 0; j < 8; ++j) {
      const int k = kbase + j;
      dst[j] = (_Float16)((k < K) ? w[k * MW + n] : 0.0f);
    }
  } else {
    // w_out (256 x 3) -> 16x16x32 B-frag, N padded to 16
    const int kt = (u - NUNIT_MAIN) >> 6;
    const int col = lane & 15;
    const int kbase = kt * 32 + (lane >> 4) * 8;
    _Float16* dst = wp + (size_t)u * 8;
#pragma unroll
    for (int j = 0; j < 8; ++j)
      dst[j] = (_Float16)((col < 3) ? wo[(kbase + j) * 3 + col] : 0.0f);
  }
}

__global__ __launch_bounds__(TPB, 4) void decoder_kernel(
    const float* __restrict__ grid, const float* __restrict__ coords,
    const float* __restrict__ b0, const float* __restrict__ b1,
    const float* __restrict__ b2, const float* __restrict__ b3,
    const float* __restrict__ bo,
    const float* __restrict__ film, const _Float16* __restrict__ wpack,
    float* __restrict__ out) {
  __shared__ _Float16 act[MT * LDK];   // 33792 B
  __shared__ float4 cco4[MT];          // 1024 B

  const int tid = threadIdx.x;
  const int lane = tid & 63;
  const int wc = tid >> 6;             // wave id = column quarter (disjoint cols!)
  const int b = blockIdx.x >> 10;
  const int n0 = (blockIdx.x & 1023) * MT;

  // ---- cross-layer B-prefetch registers ----
  f16x8 pre[4];
  auto preload = [&](const _Float16* __restrict__ wl) {
#pragma unroll
    for (int nt = 0; nt < 4; ++nt)
      pre[nt] = *(const f16x8*)(wl + ((size_t)((wc * 4 + nt) * 64 + lane)) * 8);
  };
  // layer0 kt=0 B-frags: in flight across the whole prologue
  preload(wpack + (size_t)KT0 * KTU);

  // ---- per-point bilinear setup ----
  if (tid < MT) {
    const float x = coords[(size_t)(n0 + tid) * 2 + 0];
    const float y = coords[(size_t)(n0 + tid) * 2 + 1];
    const float cr = (x + 1.0f) * 0.5f * 63.0f;
    const float cc = (y + 1.0f) * 0.5f * 63.0f;
    const float r0f = floorf(cr), q0f = floorf(cc);
    const int r0 = min(max((int)r0f, 0), GH - 1);
    const int q0 = min(max((int)q0f, 0), GW - 1);
    float4 v;
    v.x = __int_as_float(r0);
    v.y = __int_as_float(q0);
    v.z = cr - r0f;
    v.w = cc - q0f;
    cco4[tid] = v;
  }

  // ---- positional encoding (hw sin/cos, revolutions) + zero-pad 170..191 ----
  {
    const int p = tid & 63;
    const int j = tid >> 6;
    const float x = coords[(size_t)(n0 + p) * 2 + 0];
    const float y = coords[(size_t)(n0 + p) * 2 + 1];
    _Float16* row = act + p * LDK;
    if (j == 0) { row[0] = (_Float16)x; row[1] = (_Float16)y; }
    if (j == 1) {
      for (int c = ENCD + DM; c < ENCD + DM + 22; ++c) row[c] = (_Float16)0.0f;
    }
    for (int i = j; i < NF; i += 4) {
      const float sc = 0.5f * (float)(1 << i);   // x*pi*2^i rad == x*2^(i-1) rev
      const float rx = x * sc, ry = y * sc;
      const float fx = rx - floorf(rx);
      const float fy = ry - floorf(ry);
      row[2 + 4 * i + 0] = (_Float16)__builtin_amdgcn_sinf(fx);
      row[2 + 4 * i + 1] = (_Float16)__builtin_amdgcn_sinf(fy);
      row[2 + 4 * i + 2] = (_Float16)__builtin_amdgcn_cosf(fx);
      row[2 + 4 * i + 3] = (_Float16)__builtin_amdgcn_cosf(fy);
    }
  }
  __syncthreads();

  // ---- bilinear sampling, 4 channels/iter ----
  {
    const float* gb = grid + (size_t)b * (GH * GW * DM);
#pragma unroll
    for (int it = 0; it < (MT * DM / 4) / TPB; ++it) {  // 8 iters
      const int idx = it * TPB + tid;
      const int p = idx >> 5;
      const int c = (idx & 31) * 4;
      const float4 cc4 = cco4[p];
      const int r0 = __float_as_int(cc4.x);
      const int q0 = __float_as_int(cc4.y);
      const float frr = cc4.z, frc = cc4.w;
      const int r1 = min(r0 + 1, GH - 1), q1 = min(q0 + 1, GW - 1);
      const float4 v00 = *(const float4*)(gb + (size_t)(r0 * GW + q0) * DM + c);
      const float4 v01 = *(const float4*)(gb + (size_t)(r0 * GW + q1) * DM + c);
      const float4 v10 = *(const float4*)(gb + (size_t)(r1 * GW + q0) * DM + c);
      const float4 v11 = *(const float4*)(gb + (size_t)(r1 * GW + q1) * DM + c);
      float4 vt, vb, vv;
      vt.x = fmaf(v01.x - v00.x, frc, v00.x);
      vt.y = fmaf(v01.y - v00.y, frc, v00.y);
      vt.z = fmaf(v01.z - v00.z, frc, v00.z);
      vt.w = fmaf(v01.w - v00.w, frc, v00.w);
      vb.x = fmaf(v11.x - v10.x, frc, v10.x);
      vb.y = fmaf(v11.y - v10.y, frc, v10.y);
      vb.z = fmaf(v11.z - v10.z, frc, v10.z);
      vb.w = fmaf(v11.w - v10.w, frc, v10.w);
      vv.x = fmaf(vb.x - vt.x, frr, vt.x);
      vv.y = fmaf(vb.y - vt.y, frr, vt.y);
      vv.z = fmaf(vb.z - vt.z, frr, vt.z);
      vv.w = fmaf(vb.w - vt.w, frr, vt.w);
      const h16x2 lo = __builtin_amdgcn_cvt_pkrtz(vv.x, vv.y);
      const h16x2 hi = __builtin_amdgcn_cvt_pkrtz(vv.z, vv.w);
      *(h16x2*)(act + p * LDK + ENCD + c) = lo;
      *(h16x2*)(act + p * LDK + ENCD + c + 2) = hi;
    }
  }

  // ---- FiLM params for this wave's columns ----
  const int colbase = wc * 64 + (lane & 15);
  float g1[4], btv[4];
#pragma unroll
  for (int nt = 0; nt < 4; ++nt) {
    g1[nt] = film[b * 512 + colbase + nt * 16] + 1.0f;
    btv[nt] = film[b * 512 + MW + colbase + nt * 16];
  }
  __syncthreads();

  const int arow = lane & 15;
  const int kq = (lane >> 4) * 8;

  // ---- fused MLP layers (16x16x32; wave = 64 rows x 64 disjoint cols) ----
  auto run_layer = [&](const _Float16* __restrict__ wl,
                       const float* __restrict__ bl, const int Kt,
                       const _Float16* __restrict__ wnext) {
    f32x4 acc[4][4];
#pragma unroll
    for (int mt = 0; mt < 4; ++mt)
#pragma unroll
      for (int nt = 0; nt < 4; ++nt)
        acc[mt][nt] = (f32x4){0.f, 0.f, 0.f, 0.f};

    float cb[4];
#pragma unroll
    for (int nt = 0; nt < 4; ++nt)
      cb[nt] = fmaf(bl[colbase + nt * 16], g1[nt], btv[nt]);  // bias folded into FiLM

    // kt = 0: B-frags already in registers (prefetched across the barriers)
    {
      f16x8 afr[4];
#pragma unroll
      for (int mt = 0; mt < 4; ++mt)
        afr[mt] = *(const f16x8*)(act + (mt * 16 + arow) * LDK + kq);
#pragma unroll
      for (int mt = 0; mt < 4; ++mt)
#pragma unroll
        for (int nt = 0; nt < 4; ++nt)
          acc[mt][nt] = __builtin_amdgcn_mfma_f32_16x16x32_f16(afr[mt], pre[nt], acc[mt][nt], 0, 0, 0);
    }

#pragma unroll 2
    for (int kt = 1; kt < Kt; ++kt) {
      f16x8 bfr[4];
#pragma unroll
      for (int nt = 0; nt < 4; ++nt)
        bfr[nt] = *(const f16x8*)(wl + ((size_t)((kt * 16 + wc * 4 + nt) * 64 + lane)) * 8);
      f16x8 afr[4];
      const int kof = kt * 32 + kq;
#pragma unroll
      for (int mt = 0; mt < 4; ++mt)
        afr[mt] = *(const f16x8*)(act + (mt * 16 + arow) * LDK + kof);
#pragma unroll
      for (int mt = 0; mt < 4; ++mt)
#pragma unroll
        for (int nt = 0; nt < 4; ++nt)
          acc[mt][nt] = __builtin_amdgcn_mfma_f32_16x16x32_f16(afr[mt], bfr[nt], acc[mt][nt], 0, 0, 0);
    }

    // prefetch next layer's kt=0 B-frags; loads overlap epilogue + both barriers
    if (wnext) preload(wnext);

    __syncthreads();  // all waves done reading act
    // epilogue: C/D col=lane&15, row=(lane>>4)*4+r
#pragma unroll
    for (int nt = 0; nt < 4; ++nt) {
      const int col = wc * 64 + nt * 16 + (lane & 15);
#pragma unroll
      for (int mt = 0; mt < 4; ++mt) {
        const int rowb = mt * 16 + (lane >> 4) * 4;
#pragma unroll
        for (int r = 0; r < 4; ++r) {
          const float v = fmaf(acc[mt][nt][r], g1[nt], cb[nt]);
          act[(rowb + r) * LDK + col] = (_Float16)gelu_fast(v);
        }
      }
    }
    __syncthreads();
  };

  const _Float16* wp0 = wpack + (size_t)KT0 * KTU;
  const _Float16* wp1 = wpack + (size_t)KT1 * KTU;
  const _Float16* wp2 = wpack + (size_t)KT2 * KTU;
  const _Float16* wp3 = wpack + (size_t)KT3 * KTU;
  run_layer(wp0, b0, 6, wp1);
  run_layer(wp1, b1, 8, wp2);
  run_layer(wp2, b2, 8, wp3);
  run_layer(wp3, b3, 8, nullptr);

  // ---- output layer via 16x16x32 MFMA (N padded to 16) ----
  {
    f32x4 oacc = (f32x4){0.f, 0.f, 0.f, 0.f};
    const _Float16* wob = wpack + OUT_OFF;
#pragma unroll
    for (int kt = 0; kt < 8; ++kt) {
      const f16x8 bfr = *(const f16x8*)(wob + (size_t)(kt * 64 + lane) * 8);
      const f16x8 afr = *(const f16x8*)(act + (wc * 16 + arow) * LDK + kt * 32 + kq);
      oacc = __builtin_amdgcn_mfma_f32_16x16x32_f16(afr, bfr, oacc, 0, 0, 0);
    }
    const int col = lane & 15;
    if (col < 3) {
      const float bv = bo[col];
      const int rowb = wc * 16 + (lane >> 4) * 4;
#pragma unroll
      for (int r = 0; r < 4; ++r)
        out[((size_t)b * NPTS + n0 + rowb + r) * 3 + col] = tanh_fast(oacc[r] + bv);
    }
  }
}

extern "C" void kernel_launch(void* const* d_in, const int* in_sizes, int n_in,
                              void* d_out, int out_size, void* d_ws, size_t ws_size,
                              hipStream_t stream) {
  const float* grid   = (const float*)d_in[0];
  const float* ctx    = (const float*)d_in[1];
  const float* coords = (const float*)d_in[2];
  const float* w0 = (const float*)d_in[3];
  const float* b0 = (const float*)d_in[4];
  const float* w1 = (const float*)d_in[5];
  const float* b1 = (const float*)d_in[6];
  const float* w2 = (const float*)d_in[7];
  const float* b2 = (const float*)d_in[8];
  const float* w3 = (const float*)d_in[9];
  const float* b3 = (const float*)d_in[10];
  const float* wf = (const float*)d_in[11];
  const float* bf = (const float*)d_in[12];
  const float* wo = (const float*)d_in[13];
  const float* bo = (const float*)d_in[14];
  float* out = (float*)d_out;

  float* filmbuf = (float*)d_ws;
  _Float16* wpack = (_Float16*)((char*)d_ws + 8192);

  hipLaunchKernelGGL(prep_kernel, dim3(126), dim3(256), 0, stream,
                     w0, w1, w2, w3, wo, ctx, wf, bf, wpack, filmbuf);
  hipLaunchKernelGGL(decoder_kernel, dim3(NB * (NPTS / MT)), dim3(TPB), 0, stream,
                     grid, coords, b0, b1, b2, b3, bo, filmbuf, wpack, out);
}

// Round 7
// 279.581 us; speedup vs baseline: 1.1121x; 1.0384x over previous
//
#include <hip/hip_runtime.h>
#include <math.h>

#define NB 4
#define GH 64
#define GW 64
#define DM 128
#define MW 256
#define NF 10
#define NPTS 65536
#define ENCD 42
#define MT 128         // points per block
#define TPB 512
#define LDK 264        // act row stride in f16

typedef _Float16 f16x8 __attribute__((ext_vector_type(8)));
typedef __fp16 h16x2 __attribute__((ext_vector_type(2)));
typedef float f32x4 __attribute__((ext_vector_type(4)));

// d_ws: [0,8192) film fp32 (4x512); [8192,...) packed f16 weights.
// 16x16x32 B-frags: unit = (ktg*16 + nt)*64 + lane, 8 halves each.
// ktg: layer0 kt 0..5 (K pad 192), layer1 6..13, layer2 14..21, layer3 22..29.
#define KTU 8192       // halves per K=32 slab (16 ntiles * 64 * 8)
#define KT0 0
#define KT1 6
#define KT2 14
#define KT3 22
#define KT_TOTAL 30
#define NUNIT_MAIN (KT_TOTAL * 16 * 64)   // 30720 units
#define NUNIT_OUT (8 * 64)                // w_out 16x16x32 frags, 8 kt
#define OUT_OFF ((size_t)NUNIT_MAIN * 8)

__device__ __forceinline__ float gelu_fast(float v) {
  // v * sigmoid(2*sqrt(2/pi)*(v+0.044715 v^3)) via exp2+rcp
  const float t = v * v;
  const float w = fmaf(-0.10294324f, t, -2.3022082f);   // -2*log2e*c0*(1, 0.044715)
  const float e = __builtin_amdgcn_exp2f(v * w);
  return v * __builtin_amdgcn_rcpf(1.0f + e);
}

__device__ __forceinline__ float tanh_fast(float v) {
  const float e = __builtin_amdgcn_exp2f(2.8853900818f * v);  // e^(2v)
  return 1.0f - 2.0f * __builtin_amdgcn_rcpf(1.0f + e);
}

// Fused prep: blocks [0,122) pack weights; blocks [122,126) compute film.
// 122*256 = 31232 = NUNIT_MAIN + NUNIT_OUT exactly.
__global__ void prep_kernel(const float* __restrict__ w0, const float* __restrict__ w1,
                            const float* __restrict__ w2, const float* __restrict__ w3,
                            const float* __restrict__ wo,
                            const float* __restrict__ ctx, const float* __restrict__ wf,
                            const float* __restrict__ bf,
                            _Float16* __restrict__ wp, float* __restrict__ filmout) {
  if (blockIdx.x >= 122) {
    const int b = blockIdx.x - 122;
#pragma unroll
    for (int h = 0; h < 2; ++h) {
      const int j = threadIdx.x + h * 256;
      float acc = bf[j];
      for (int k = 0; k < DM; ++k)
        acc = fmaf(ctx[b * DM + k], wf[k * 512 + j], acc);
      filmout[b * 512 + j] = acc;
    }
    return;
  }
  const int u = blockIdx.x * 256 + threadIdx.x;
  const int lane = u & 63;
  if (u < NUNIT_MAIN) {
    const int v = u >> 6;
    const int nt = v & 15;
    const int ktg = v >> 4;
    const float* w; int ktl, K;
    if (ktg < KT1)      { w = w0; ktl = ktg - KT0; K = 170; }
    else if (ktg < KT2) { w = w1; ktl = ktg - KT1; K = 256; }
    else if (ktg < KT3) { w = w2; ktl = ktg - KT2; K = 256; }
    else                { w = w3; ktl = ktg - KT3; K = 256; }
    const int n = nt * 16 + (lane & 15);
    const int kbase = ktl * 32 + (lane >> 4) * 8;
    _Float16* dst = wp + (size_t)u * 8;
#pragma unroll
    for (int j = 0; j < 8; ++j) {
      const int k = kbase + j;
      dst[j] = (_Float16)((k < K) ? w[k * MW + n] : 0.0f);
    }
  } else {
    // w_out (256 x 3) -> 16x16x32 B-frag, N padded to 16
    const int kt = (u - NUNIT_MAIN) >> 6;
    const int col = lane & 15;
    const int kbase = kt * 32 + (lane >> 4) * 8;
    _Float16* dst = wp + (size_t)u * 8;
#pragma unroll
    for (int j = 0; j < 8; ++j)
      dst[j] = (_Float16)((col < 3) ? wo[(kbase + j) * 3 + col] : 0.0f);
  }
}

__global__ __launch_bounds__(TPB, 4) void decoder_kernel(
    const float* __restrict__ grid, const float* __restrict__ coords,
    const float* __restrict__ b0, const float* __restrict__ b1,
    const float* __restrict__ b2, const float* __restrict__ b3,
    const float* __restrict__ bo,
    const float* __restrict__ film, const _Float16* __restrict__ wpack,
    float* __restrict__ out) {
  __shared__ _Float16 act[MT * LDK];   // 67584 B
  __shared__ float4 cco4[MT];          // 2048 B

  const int tid = threadIdx.x;
  const int lane = tid & 63;
  const int wc = tid >> 6;             // wave 0..7
  const int wn = wc & 3;               // column quarter (disjoint cols per wave!)
  const int wr = wc >> 2;              // row half (64 rows each)
  const int b = blockIdx.x >> 9;       // 512 tiles per batch
  const int n0 = (blockIdx.x & 511) * MT;

  // ---- per-point bilinear setup ----
  if (tid < MT) {
    const float x = coords[(size_t)(n0 + tid) * 2 + 0];
    const float y = coords[(size_t)(n0 + tid) * 2 + 1];
    const float cr = (x + 1.0f) * 0.5f * 63.0f;
    const float cc = (y + 1.0f) * 0.5f * 63.0f;
    const float r0f = floorf(cr), q0f = floorf(cc);
    const int r0 = min(max((int)r0f, 0), GH - 1);
    const int q0 = min(max((int)q0f, 0), GW - 1);
    float4 v;
    v.x = __int_as_float(r0);
    v.y = __int_as_float(q0);
    v.z = cr - r0f;
    v.w = cc - q0f;
    cco4[tid] = v;
  }

  // ---- positional encoding (hw sin/cos, revolutions) + zero-pad 170..191 ----
  {
    const int p = tid & (MT - 1);
    const int j = tid >> 7;  // 0..3
    const float x = coords[(size_t)(n0 + p) * 2 + 0];
    const float y = coords[(size_t)(n0 + p) * 2 + 1];
    _Float16* row = act + p * LDK;
    if (j == 0) { row[0] = (_Float16)x; row[1] = (_Float16)y; }
    if (j == 1) {
      for (int c = ENCD + DM; c < ENCD + DM + 22; ++c) row[c] = (_Float16)0.0f;
    }
    for (int i = j; i < NF; i += 4) {
      const float sc = 0.5f * (float)(1 << i);   // x*pi*2^i rad == x*2^(i-1) rev
      const float rx = x * sc, ry = y * sc;
      const float fx = rx - floorf(rx);
      const float fy = ry - floorf(ry);
      row[2 + 4 * i + 0] = (_Float16)__builtin_amdgcn_sinf(fx);
      row[2 + 4 * i + 1] = (_Float16)__builtin_amdgcn_sinf(fy);
      row[2 + 4 * i + 2] = (_Float16)__builtin_amdgcn_cosf(fx);
      row[2 + 4 * i + 3] = (_Float16)__builtin_amdgcn_cosf(fy);
    }
  }
  __syncthreads();

  // ---- bilinear sampling, 4 channels/iter ----
  {
    const float* gb = grid + (size_t)b * (GH * GW * DM);
#pragma unroll
    for (int it = 0; it < (MT * DM / 4) / TPB; ++it) {  // 8 iters
      const int idx = it * TPB + tid;
      const int p = idx >> 5;
      const int c = (idx & 31) * 4;
      const float4 cc4 = cco4[p];
      const int r0 = __float_as_int(cc4.x);
      const int q0 = __float_as_int(cc4.y);
      const float frr = cc4.z, frc = cc4.w;
      const int r1 = min(r0 + 1, GH - 1), q1 = min(q0 + 1, GW - 1);
      const float4 v00 = *(const float4*)(gb + (size_t)(r0 * GW + q0) * DM + c);
      const float4 v01 = *(const float4*)(gb + (size_t)(r0 * GW + q1) * DM + c);
      const float4 v10 = *(const float4*)(gb + (size_t)(r1 * GW + q0) * DM + c);
      const float4 v11 = *(const float4*)(gb + (size_t)(r1 * GW + q1) * DM + c);
      float4 vt, vb, vv;
      vt.x = fmaf(v01.x - v00.x, frc, v00.x);
      vt.y = fmaf(v01.y - v00.y, frc, v00.y);
      vt.z = fmaf(v01.z - v00.z, frc, v00.z);
      vt.w = fmaf(v01.w - v00.w, frc, v00.w);
      vb.x = fmaf(v11.x - v10.x, frc, v10.x);
      vb.y = fmaf(v11.y - v10.y, frc, v10.y);
      vb.z = fmaf(v11.z - v10.z, frc, v10.z);
      vb.w = fmaf(v11.w - v10.w, frc, v10.w);
      vv.x = fmaf(vb.x - vt.x, frr, vt.x);
      vv.y = fmaf(vb.y - vt.y, frr, vt.y);
      vv.z = fmaf(vb.z - vt.z, frr, vt.z);
      vv.w = fmaf(vb.w - vt.w, frr, vt.w);
      const h16x2 lo = __builtin_amdgcn_cvt_pkrtz(vv.x, vv.y);
      const h16x2 hi = __builtin_amdgcn_cvt_pkrtz(vv.z, vv.w);
      *(h16x2*)(act + p * LDK + ENCD + c) = lo;
      *(h16x2*)(act + p * LDK + ENCD + c + 2) = hi;
    }
  }

  // ---- FiLM params for this wave's columns ----
  const int colbase = wn * 64 + (lane & 15);
  float g1[4], btv[4];
#pragma unroll
  for (int nt = 0; nt < 4; ++nt) {
    g1[nt] = film[b * 512 + colbase + nt * 16] + 1.0f;
    btv[nt] = film[b * 512 + MW + colbase + nt * 16];
  }
  __syncthreads();

  const int arowb = wr * 64 + (lane & 15);   // A-row base for this wave
  const int kq = (lane >> 4) * 8;

  // ---- fused MLP layers (16x16x32; wave = 64 rows x 64 disjoint cols) ----
  auto run_layer = [&](const _Float16* __restrict__ wl,
                       const float* __restrict__ bl, const int Kt) {
    f32x4 acc[4][4];
#pragma unroll
    for (int mt = 0; mt < 4; ++mt)
#pragma unroll
      for (int nt = 0; nt < 4; ++nt)
        acc[mt][nt] = (f32x4){0.f, 0.f, 0.f, 0.f};

    float cb[4];
#pragma unroll
    for (int nt = 0; nt < 4; ++nt)
      cb[nt] = fmaf(bl[colbase + nt * 16], g1[nt], btv[nt]);  // bias folded into FiLM

#pragma unroll 2
    for (int kt = 0; kt < Kt; ++kt) {
      f16x8 bfr[4];
#pragma unroll
      for (int nt = 0; nt < 4; ++nt)
        bfr[nt] = *(const f16x8*)(wl + ((size_t)((kt * 16 + wn * 4 + nt) * 64 + lane)) * 8);
      f16x8 afr[4];
      const int kof = kt * 32 + kq;
#pragma unroll
      for (int mt = 0; mt < 4; ++mt)
        afr[mt] = *(const f16x8*)(act + (arowb + mt * 16) * LDK + kof);
#pragma unroll
      for (int mt = 0; mt < 4; ++mt)
#pragma unroll
        for (int nt = 0; nt < 4; ++nt)
          acc[mt][nt] = __builtin_amdgcn_mfma_f32_16x16x32_f16(afr[mt], bfr[nt], acc[mt][nt], 0, 0, 0);
    }

    __syncthreads();  // all waves done reading act
    // epilogue: C/D col=lane&15, row=(lane>>4)*4+r
#pragma unroll
    for (int nt = 0; nt < 4; ++nt) {
      const int col = wn * 64 + nt * 16 + (lane & 15);
#pragma unroll
      for (int mt = 0; mt < 4; ++mt) {
        const int rowb = wr * 64 + mt * 16 + (lane >> 4) * 4;
#pragma unroll
        for (int r = 0; r < 4; ++r) {
          const float v = fmaf(acc[mt][nt][r], g1[nt], cb[nt]);
          act[(rowb + r) * LDK + col] = (_Float16)gelu_fast(v);
        }
      }
    }
    __syncthreads();
  };

  run_layer(wpack + (size_t)KT0 * KTU, b0, 6);
  run_layer(wpack + (size_t)KT1 * KTU, b1, 8);
  run_layer(wpack + (size_t)KT2 * KTU, b2, 8);
  run_layer(wpack + (size_t)KT3 * KTU, b3, 8);

  // ---- output layer via 16x16x32 MFMA (N padded to 16); wave wc -> rows wc*16.. ----
  {
    f32x4 oacc = (f32x4){0.f, 0.f, 0.f, 0.f};
    const _Float16* wob = wpack + OUT_OFF;
    const int arow16 = lane & 15;
#pragma unroll
    for (int kt = 0; kt < 8; ++kt) {
      const f16x8 bfr = *(const f16x8*)(wob + (size_t)(kt * 64 + lane) * 8);
      const f16x8 afr = *(const f16x8*)(act + (wc * 16 + arow16) * LDK + kt * 32 + kq);
      oacc = __builtin_amdgcn_mfma_f32_16x16x32_f16(afr, bfr, oacc, 0, 0, 0);
    }
    const int col = lane & 15;
    if (col < 3) {
      const float bv = bo[col];
      const int rowb = wc * 16 + (lane >> 4) * 4;
#pragma unroll
      for (int r = 0; r < 4; ++r)
        out[((size_t)b * NPTS + n0 + rowb + r) * 3 + col] = tanh_fast(oacc[r] + bv);
    }
  }
}

extern "C" void kernel_launch(void* const* d_in, const int* in_sizes, int n_in,
                              void* d_out, int out_size, void* d_ws, size_t ws_size,
                              hipStream_t stream) {
  const float* grid   = (const float*)d_in[0];
  const float* ctx    = (const float*)d_in[1];
  const float* coords = (const float*)d_in[2];
  const float* w0 = (const float*)d_in[3];
  const float* b0 = (const float*)d_in[4];
  const float* w1 = (const float*)d_in[5];
  const float* b1 = (const float*)d_in[6];
  const float* w2 = (const float*)d_in[7];
  const float* b2 = (const float*)d_in[8];
  const float* w3 = (const float*)d_in[9];
  const float* b3 = (const float*)d_in[10];
  const float* wf = (const float*)d_in[11];
  const float* bf = (const float*)d_in[12];
  const float* wo = (const float*)d_in[13];
  const float* bo = (const float*)d_in[14];
  float* out = (float*)d_out;

  float* filmbuf = (float*)d_ws;
  _Float16* wpack = (_Float16*)((char*)d_ws + 8192);

  hipLaunchKernelGGL(prep_kernel, dim3(126), dim3(256), 0, stream,
                     w0, w1, w2, w3, wo, ctx, wf, bf, wpack, filmbuf);
  hipLaunchKernelGGL(decoder_kernel, dim3(NB * (NPTS / MT)), dim3(TPB), 0, stream,
                     grid, coords, b0, b1, b2, b3, bo, filmbuf, wpack, out);
}

// Round 8
// 271.644 us; speedup vs baseline: 1.1446x; 1.0292x over previous
//
#include <hip/hip_runtime.h>
#include <math.h>

#define NB 4
#define GH 64
#define GW 64
#define DM 128
#define MW 256
#define NF 10
#define NPTS 65536
#define ENCD 42
#define MT 128         // points per block: two 64-pt half-tiles A (rows 0-63) and B (64-127)
#define TPB 512
#define LDK 264        // act row stride in f16

typedef _Float16 f16x8 __attribute__((ext_vector_type(8)));
typedef __fp16 h16x2 __attribute__((ext_vector_type(2)));
typedef float f32x4 __attribute__((ext_vector_type(4)));

// d_ws: [0,8192) film fp32 (4x512); [8192,...) packed f16 weights.
// 16x16x32 B-frags: unit = (ktg*16 + nt)*64 + lane, 8 halves each.
#define KTU 8192
#define KT0 0
#define KT1 6
#define KT2 14
#define KT3 22
#define KT_TOTAL 30
#define NUNIT_MAIN (KT_TOTAL * 16 * 64)
#define NUNIT_OUT (8 * 64)
#define OUT_OFF ((size_t)NUNIT_MAIN * 8)

__device__ __forceinline__ float gelu_fast(float v) {
  const float t = v * v;
  const float w = fmaf(-0.10294324f, t, -2.3022082f);
  const float e = __builtin_amdgcn_exp2f(v * w);
  return v * __builtin_amdgcn_rcpf(1.0f + e);
}

__device__ __forceinline__ float tanh_fast(float v) {
  const float e = __builtin_amdgcn_exp2f(2.8853900818f * v);
  return 1.0f - 2.0f * __builtin_amdgcn_rcpf(1.0f + e);
}

// Fused prep: blocks [0,122) pack weights; blocks [122,126) compute film.
__global__ void prep_kernel(const float* __restrict__ w0, const float* __restrict__ w1,
                            const float* __restrict__ w2, const float* __restrict__ w3,
                            const float* __restrict__ wo,
                            const float* __restrict__ ctx, const float* __restrict__ wf,
                            const float* __restrict__ bf,
                            _Float16* __restrict__ wp, float* __restrict__ filmout) {
  if (blockIdx.x >= 122) {
    const int b = blockIdx.x - 122;
#pragma unroll
    for (int h = 0; h < 2; ++h) {
      const int j = threadIdx.x + h * 256;
      float acc = bf[j];
      for (int k = 0; k < DM; ++k)
        acc = fmaf(ctx[b * DM + k], wf[k * 512 + j], acc);
      filmout[b * 512 + j] = acc;
    }
    return;
  }
  const int u = blockIdx.x * 256 + threadIdx.x;
  const int lane = u & 63;
  if (u < NUNIT_MAIN) {
    const int v = u >> 6;
    const int nt = v & 15;
    const int ktg = v >> 4;
    const float* w; int ktl, K;
    if (ktg < KT1)      { w = w0; ktl = ktg - KT0; K = 170; }
    else if (ktg < KT2) { w = w1; ktl = ktg - KT1; K = 256; }
    else if (ktg < KT3) { w = w2; ktl = ktg - KT2; K = 256; }
    else                { w = w3; ktl = ktg - KT3; K = 256; }
    const int n = nt * 16 + (lane & 15);
    const int kbase = ktl * 32 + (lane >> 4) * 8;
    _Float16* dst = wp + (size_t)u * 8;
#pragma unroll
    for (int j = 0; j < 8; ++j) {
      const int k = kbase + j;
      dst[j] = (_Float16)((k < K) ? w[k * MW + n] : 0.0f);
    }
  } else {
    const int kt = (u - NUNIT_MAIN) >> 6;
    const int col = lane & 15;
    const int kbase = kt * 32 + (lane >> 4) * 8;
    _Float16* dst = wp + (size_t)u * 8;
#pragma unroll
    for (int j = 0; j < 8; ++j)
      dst[j] = (_Float16)((col < 3) ? wo[(kbase + j) * 3 + col] : 0.0f);
  }
}

__global__ __launch_bounds__(TPB, 4) void decoder_kernel(
    const float* __restrict__ grid, const float* __restrict__ coords,
    const float* __restrict__ b0, const float* __restrict__ b1,
    const float* __restrict__ b2, const float* __restrict__ b3,
    const float* __restrict__ bo,
    const float* __restrict__ film, const _Float16* __restrict__ wpack,
    float* __restrict__ out) {
  __shared__ _Float16 act[MT * LDK];   // 67584 B; rows 0-63 = tile A, 64-127 = tile B
  __shared__ float4 cco4[MT];          // 2048 B

  const int tid = threadIdx.x;
  const int lane = tid & 63;
  const int wc = tid >> 6;             // wave 0..7: owns cols wc*32..wc*32+31 (disjoint)
  const int b = blockIdx.x >> 9;
  const int n0 = (blockIdx.x & 511) * MT;

  // ---- per-point bilinear setup ----
  if (tid < MT) {
    const float x = coords[(size_t)(n0 + tid) * 2 + 0];
    const float y = coords[(size_t)(n0 + tid) * 2 + 1];
    const float cr = (x + 1.0f) * 0.5f * 63.0f;
    const float cc = (y + 1.0f) * 0.5f * 63.0f;
    const float r0f = floorf(cr), q0f = floorf(cc);
    const int r0 = min(max((int)r0f, 0), GH - 1);
    const int q0 = min(max((int)q0f, 0), GW - 1);
    float4 v;
    v.x = __int_as_float(r0);
    v.y = __int_as_float(q0);
    v.z = cr - r0f;
    v.w = cc - q0f;
    cco4[tid] = v;
  }

  // ---- positional encoding (hw sin/cos, revolutions) + zero-pad 170..191 ----
  {
    const int p = tid & (MT - 1);
    const int j = tid >> 7;
    const float x = coords[(size_t)(n0 + p) * 2 + 0];
    const float y = coords[(size_t)(n0 + p) * 2 + 1];
    _Float16* row = act + p * LDK;
    if (j == 0) { row[0] = (_Float16)x; row[1] = (_Float16)y; }
    if (j == 1) {
      for (int c = ENCD + DM; c < ENCD + DM + 22; ++c) row[c] = (_Float16)0.0f;
    }
    for (int i = j; i < NF; i += 4) {
      const float sc = 0.5f * (float)(1 << i);
      const float rx = x * sc, ry = y * sc;
      const float fx = rx - floorf(rx);
      const float fy = ry - floorf(ry);
      row[2 + 4 * i + 0] = (_Float16)__builtin_amdgcn_sinf(fx);
      row[2 + 4 * i + 1] = (_Float16)__builtin_amdgcn_sinf(fy);
      row[2 + 4 * i + 2] = (_Float16)__builtin_amdgcn_cosf(fx);
      row[2 + 4 * i + 3] = (_Float16)__builtin_amdgcn_cosf(fy);
    }
  }
  __syncthreads();

  // ---- bilinear sampling, 4 channels/iter ----
  {
    const float* gb = grid + (size_t)b * (GH * GW * DM);
#pragma unroll
    for (int it = 0; it < (MT * DM / 4) / TPB; ++it) {
      const int idx = it * TPB + tid;
      const int p = idx >> 5;
      const int c = (idx & 31) * 4;
      const float4 cc4 = cco4[p];
      const int r0 = __float_as_int(cc4.x);
      const int q0 = __float_as_int(cc4.y);
      const float frr = cc4.z, frc = cc4.w;
      const int r1 = min(r0 + 1, GH - 1), q1 = min(q0 + 1, GW - 1);
      const float4 v00 = *(const float4*)(gb + (size_t)(r0 * GW + q0) * DM + c);
      const float4 v01 = *(const float4*)(gb + (size_t)(r0 * GW + q1) * DM + c);
      const float4 v10 = *(const float4*)(gb + (size_t)(r1 * GW + q0) * DM + c);
      const float4 v11 = *(const float4*)(gb + (size_t)(r1 * GW + q1) * DM + c);
      float4 vt, vb, vv;
      vt.x = fmaf(v01.x - v00.x, frc, v00.x);
      vt.y = fmaf(v01.y - v00.y, frc, v00.y);
      vt.z = fmaf(v01.z - v00.z, frc, v00.z);
      vt.w = fmaf(v01.w - v00.w, frc, v00.w);
      vb.x = fmaf(v11.x - v10.x, frc, v10.x);
      vb.y = fmaf(v11.y - v10.y, frc, v10.y);
      vb.z = fmaf(v11.z - v10.z, frc, v10.z);
      vb.w = fmaf(v11.w - v10.w, frc, v10.w);
      vv.x = fmaf(vb.x - vt.x, frr, vt.x);
      vv.y = fmaf(vb.y - vt.y, frr, vt.y);
      vv.z = fmaf(vb.z - vt.z, frr, vt.z);
      vv.w = fmaf(vb.w - vt.w, frr, vt.w);
      const h16x2 lo = __builtin_amdgcn_cvt_pkrtz(vv.x, vv.y);
      const h16x2 hi = __builtin_amdgcn_cvt_pkrtz(vv.z, vv.w);
      *(h16x2*)(act + p * LDK + ENCD + c) = lo;
      *(h16x2*)(act + p * LDK + ENCD + c + 2) = hi;
    }
  }

  // ---- FiLM params: this wave owns 2 n-tiles (cols wc*32 + nt*16 + 0..15) ----
  const int colbase = wc * 32 + (lane & 15);
  float g1[2], btv[2];
#pragma unroll
  for (int nt = 0; nt < 2; ++nt) {
    g1[nt] = film[b * 512 + colbase + nt * 16] + 1.0f;
    btv[nt] = film[b * 512 + MW + colbase + nt * 16];
  }
  __syncthreads();

  const int arow = lane & 15;
  const int kq = (lane >> 4) * 8;

  f32x4 accA[4][2], accB[4][2];

  // one K-step of the MFMA loop for tile T into acc
  auto kstep = [&](const _Float16* __restrict__ wl, int kt, int T,
                   f32x4 (&acc)[4][2]) {
    f16x8 bfr[2];
#pragma unroll
    for (int nt = 0; nt < 2; ++nt)
      bfr[nt] = *(const f16x8*)(wl + ((size_t)((kt * 16 + wc * 2 + nt) * 64 + lane)) * 8);
    f16x8 afr[4];
    const int kof = kt * 32 + kq;
#pragma unroll
    for (int mt = 0; mt < 4; ++mt)
      afr[mt] = *(const f16x8*)(act + (T * 64 + mt * 16 + arow) * LDK + kof);
#pragma unroll
    for (int mt = 0; mt < 4; ++mt)
#pragma unroll
      for (int nt = 0; nt < 2; ++nt)
        acc[mt][nt] = __builtin_amdgcn_mfma_f32_16x16x32_f16(afr[mt], bfr[nt], acc[mt][nt], 0, 0, 0);
  };

  // one epilogue group (of 8) for tile T: g -> (mt = g>>1, nt = g&1)
  auto epi_group = [&](int g, int T, f32x4 (&acc)[4][2], const float* cbv) {
    const int mt = g >> 1, nt = g & 1;
    const int col = wc * 32 + nt * 16 + (lane & 15);
    const int rowb = T * 64 + mt * 16 + (lane >> 4) * 4;
#pragma unroll
    for (int r = 0; r < 4; ++r) {
      const float v = fmaf(acc[mt][nt][r], g1[nt], cbv[nt]);
      act[(rowb + r) * LDK + col] = (_Float16)gelu_fast(v);
    }
  };

  auto zero = [&](f32x4 (&acc)[4][2]) {
#pragma unroll
    for (int mt = 0; mt < 4; ++mt)
#pragma unroll
      for (int nt = 0; nt < 2; ++nt)
        acc[mt][nt] = (f32x4){0.f, 0.f, 0.f, 0.f};
  };

  const _Float16* wp0 = wpack + (size_t)KT0 * KTU;
  const _Float16* wp1 = wpack + (size_t)KT1 * KTU;
  const _Float16* wp2 = wpack + (size_t)KT2 * KTU;
  const _Float16* wp3 = wpack + (size_t)KT3 * KTU;

  float cbv[2];
  auto set_cb = [&](const float* __restrict__ bl) {
#pragma unroll
    for (int nt = 0; nt < 2; ++nt)
      cbv[nt] = fmaf(bl[colbase + nt * 16], g1[nt], btv[nt]);
  };

  // seg0: K(A,0)
  zero(accA);
#pragma unroll
  for (int kt = 0; kt < 6; ++kt) kstep(wp0, kt, 0, accA);
  __syncthreads();

  // seg1: E(A,0) + K(B,0)
  zero(accB); set_cb(b0);
#pragma unroll
  for (int s = 0; s < 8; ++s) {
    if (s < 6) kstep(wp0, s, 1, accB);
    epi_group(s, 0, accA, cbv);
  }
  __syncthreads();

  // seg2: E(B,0) + K(A,1)
  zero(accA); set_cb(b0);
#pragma unroll
  for (int s = 0; s < 8; ++s) {
    kstep(wp1, s, 0, accA);
    epi_group(s, 1, accB, cbv);
  }
  __syncthreads();

  // seg3: E(A,1) + K(B,1)
  zero(accB); set_cb(b1);
#pragma unroll
  for (int s = 0; s < 8; ++s) {
    kstep(wp1, s, 1, accB);
    epi_group(s, 0, accA, cbv);
  }
  __syncthreads();

  // seg4: E(B,1) + K(A,2)
  zero(accA); set_cb(b1);
#pragma unroll
  for (int s = 0; s < 8; ++s) {
    kstep(wp2, s, 0, accA);
    epi_group(s, 1, accB, cbv);
  }
  __syncthreads();

  // seg5: E(A,2) + K(B,2)
  zero(accB); set_cb(b2);
#pragma unroll
  for (int s = 0; s < 8; ++s) {
    kstep(wp2, s, 1, accB);
    epi_group(s, 0, accA, cbv);
  }
  __syncthreads();

  // seg6: E(B,2) + K(A,3)
  zero(accA); set_cb(b2);
#pragma unroll
  for (int s = 0; s < 8; ++s) {
    kstep(wp3, s, 0, accA);
    epi_group(s, 1, accB, cbv);
  }
  __syncthreads();

  // seg7: E(A,3) + K(B,3)
  zero(accB); set_cb(b3);
#pragma unroll
  for (int s = 0; s < 8; ++s) {
    kstep(wp3, s, 1, accB);
    epi_group(s, 0, accA, cbv);
  }
  __syncthreads();

  // seg8: E(B,3) [all waves] + Kout(tile A) [waves 0..3] + store A
  {
    set_cb(b3);
    const _Float16* wob = wpack + OUT_OFF;
    f32x4 oacc = (f32x4){0.f, 0.f, 0.f, 0.f};
    const int rb = (wc & 3) * 16 + ((wc < 4) ? 0 : 64);  // wave's 16-row slice
#pragma unroll
    for (int s = 0; s < 8; ++s) {
      if (wc < 4) {
        const f16x8 bfr = *(const f16x8*)(wob + (size_t)(s * 64 + lane) * 8);
        const f16x8 afr = *(const f16x8*)(act + (rb + arow) * LDK + s * 32 + kq);
        oacc = __builtin_amdgcn_mfma_f32_16x16x32_f16(afr, bfr, oacc, 0, 0, 0);
      }
      epi_group(s, 1, accB, cbv);
    }
    if (wc < 4) {
      const int col = lane & 15;
      if (col < 3) {
        const float bv = bo[col];
        const int rowb = rb + (lane >> 4) * 4;
#pragma unroll
        for (int r = 0; r < 4; ++r)
          out[((size_t)b * NPTS + n0 + rowb + r) * 3 + col] = tanh_fast(oacc[r] + bv);
      }
    }
    __syncthreads();

    // seg9: Kout(tile B) [waves 4..7] + store B
    if (wc >= 4) {
      f32x4 oacc2 = (f32x4){0.f, 0.f, 0.f, 0.f};
#pragma unroll
      for (int kt = 0; kt < 8; ++kt) {
        const f16x8 bfr = *(const f16x8*)(wob + (size_t)(kt * 64 + lane) * 8);
        const f16x8 afr = *(const f16x8*)(act + (rb + arow) * LDK + kt * 32 + kq);
        oacc2 = __builtin_amdgcn_mfma_f32_16x16x32_f16(afr, bfr, oacc2, 0, 0, 0);
      }
      const int col = lane & 15;
      if (col < 3) {
        const float bv = bo[col];
        const int rowb = rb + (lane >> 4) * 4;
#pragma unroll
        for (int r = 0; r < 4; ++r)
          out[((size_t)b * NPTS + n0 + rowb + r) * 3 + col] = tanh_fast(oacc2[r] + bv);
      }
    }
  }
}

extern "C" void kernel_launch(void* const* d_in, const int* in_sizes, int n_in,
                              void* d_out, int out_size, void* d_ws, size_t ws_size,
                              hipStream_t stream) {
  const float* grid   = (const float*)d_in[0];
  const float* ctx    = (const float*)d_in[1];
  const float* coords = (const float*)d_in[2];
  const float* w0 = (const float*)d_in[3];
  const float* b0 = (const float*)d_in[4];
  const float* w1 = (const float*)d_in[5];
  const float* b1 = (const float*)d_in[6];
  const float* w2 = (const float*)d_in[7];
  const float* b2 = (const float*)d_in[8];
  const float* w3 = (const float*)d_in[9];
  const float* b3 = (const float*)d_in[10];
  const float* wf = (const float*)d_in[11];
  const float* bf = (const float*)d_in[12];
  const float* wo = (const float*)d_in[13];
  const float* bo = (const float*)d_in[14];
  float* out = (float*)d_out;

  float* filmbuf = (float*)d_ws;
  _Float16* wpack = (_Float16*)((char*)d_ws + 8192);

  hipLaunchKernelGGL(prep_kernel, dim3(126), dim3(256), 0, stream,
                     w0, w1, w2, w3, wo, ctx, wf, bf, wpack, filmbuf);
  hipLaunchKernelGGL(decoder_kernel, dim3(NB * (NPTS / MT)), dim3(TPB), 0, stream,
                     grid, coords, b0, b1, b2, b3, bo, filmbuf, wpack, out);
}

// Round 9
// 269.184 us; speedup vs baseline: 1.1550x; 1.0091x over previous
//
#include <hip/hip_runtime.h>
#include <math.h>

#define NB 4
#define GH 64
#define GW 64
#define DM 128
#define MW 256
#define NF 10
#define NPTS 65536
#define ENCD 42
#define MT 128         // points per block: two 64-pt half-tiles A (rows 0-63) and B (64-127)
#define TPB 512
#define LDK 264        // act row stride in f16

typedef _Float16 f16x8 __attribute__((ext_vector_type(8)));
typedef __fp16 h16x2 __attribute__((ext_vector_type(2)));
typedef float f32x4 __attribute__((ext_vector_type(4)));

// d_ws: [0,8192) film fp32 (4x512); [8192,...) packed f16 weights.
// 16x16x32 B-frags: unit = (ktg*16 + nt)*64 + lane, 8 halves each.
#define KTU 8192
#define KT0 0
#define KT1 6
#define KT2 14
#define KT3 22
#define KT_TOTAL 30
#define NUNIT_MAIN (KT_TOTAL * 16 * 64)
#define NUNIT_OUT (8 * 64)
#define OUT_OFF ((size_t)NUNIT_MAIN * 8)

__device__ __forceinline__ float gelu_fast(float v) {
  const float t = v * v;
  const float w = fmaf(-0.10294324f, t, -2.3022082f);
  const float e = __builtin_amdgcn_exp2f(v * w);
  return v * __builtin_amdgcn_rcpf(1.0f + e);
}

__device__ __forceinline__ float tanh_fast(float v) {
  const float e = __builtin_amdgcn_exp2f(2.8853900818f * v);
  return 1.0f - 2.0f * __builtin_amdgcn_rcpf(1.0f + e);
}

// Fused prep: blocks [0,122) pack weights; blocks [122,126) compute film.
__global__ void prep_kernel(const float* __restrict__ w0, const float* __restrict__ w1,
                            const float* __restrict__ w2, const float* __restrict__ w3,
                            const float* __restrict__ wo,
                            const float* __restrict__ ctx, const float* __restrict__ wf,
                            const float* __restrict__ bf,
                            _Float16* __restrict__ wp, float* __restrict__ filmout) {
  if (blockIdx.x >= 122) {
    const int b = blockIdx.x - 122;
#pragma unroll
    for (int h = 0; h < 2; ++h) {
      const int j = threadIdx.x + h * 256;
      float acc = bf[j];
      for (int k = 0; k < DM; ++k)
        acc = fmaf(ctx[b * DM + k], wf[k * 512 + j], acc);
      filmout[b * 512 + j] = acc;
    }
    return;
  }
  const int u = blockIdx.x * 256 + threadIdx.x;
  const int lane = u & 63;
  if (u < NUNIT_MAIN) {
    const int v = u >> 6;
    const int nt = v & 15;
    const int ktg = v >> 4;
    const float* w; int ktl, K;
    if (ktg < KT1)      { w = w0; ktl = ktg - KT0; K = 170; }
    else if (ktg < KT2) { w = w1; ktl = ktg - KT1; K = 256; }
    else if (ktg < KT3) { w = w2; ktl = ktg - KT2; K = 256; }
    else                { w = w3; ktl = ktg - KT3; K = 256; }
    const int n = nt * 16 + (lane & 15);
    const int kbase = ktl * 32 + (lane >> 4) * 8;
    _Float16* dst = wp + (size_t)u * 8;
#pragma unroll
    for (int j = 0; j < 8; ++j) {
      const int k = kbase + j;
      dst[j] = (_Float16)((k < K) ? w[k * MW + n] : 0.0f);
    }
  } else {
    const int kt = (u - NUNIT_MAIN) >> 6;
    const int col = lane & 15;
    const int kbase = kt * 32 + (lane >> 4) * 8;
    _Float16* dst = wp + (size_t)u * 8;
#pragma unroll
    for (int j = 0; j < 8; ++j)
      dst[j] = (_Float16)((col < 3) ? wo[(kbase + j) * 3 + col] : 0.0f);
  }
}

__global__ __launch_bounds__(TPB, 4) void decoder_kernel(
    const float* __restrict__ grid, const float* __restrict__ coords,
    const float* __restrict__ b0, const float* __restrict__ b1,
    const float* __restrict__ b2, const float* __restrict__ b3,
    const float* __restrict__ bo,
    const float* __restrict__ film, const _Float16* __restrict__ wpack,
    float* __restrict__ out) {
  __shared__ _Float16 act[MT * LDK];   // 67584 B; rows 0-63 = tile A, 64-127 = tile B
  __shared__ float4 cco4[MT];          // 2048 B

  const int tid = threadIdx.x;
  const int lane = tid & 63;
  const int wc = tid >> 6;             // wave 0..7: owns cols wc*32..wc*32+31 (disjoint)
  const int b = blockIdx.x >> 9;
  const int n0 = (blockIdx.x & 511) * MT;

  // ---- per-point bilinear setup ----
  if (tid < MT) {
    const float x = coords[(size_t)(n0 + tid) * 2 + 0];
    const float y = coords[(size_t)(n0 + tid) * 2 + 1];
    const float cr = (x + 1.0f) * 0.5f * 63.0f;
    const float cc = (y + 1.0f) * 0.5f * 63.0f;
    const float r0f = floorf(cr), q0f = floorf(cc);
    const int r0 = min(max((int)r0f, 0), GH - 1);
    const int q0 = min(max((int)q0f, 0), GW - 1);
    float4 v;
    v.x = __int_as_float(r0);
    v.y = __int_as_float(q0);
    v.z = cr - r0f;
    v.w = cc - q0f;
    cco4[tid] = v;
  }

  // ---- positional encoding (hw sin/cos, revolutions) + zero-pad 170..191 ----
  {
    const int p = tid & (MT - 1);
    const int j = tid >> 7;
    const float x = coords[(size_t)(n0 + p) * 2 + 0];
    const float y = coords[(size_t)(n0 + p) * 2 + 1];
    _Float16* row = act + p * LDK;
    if (j == 0) { row[0] = (_Float16)x; row[1] = (_Float16)y; }
    if (j == 1) {
      for (int c = ENCD + DM; c < ENCD + DM + 22; ++c) row[c] = (_Float16)0.0f;
    }
    for (int i = j; i < NF; i += 4) {
      const float sc = 0.5f * (float)(1 << i);
      const float rx = x * sc, ry = y * sc;
      const float fx = rx - floorf(rx);
      const float fy = ry - floorf(ry);
      row[2 + 4 * i + 0] = (_Float16)__builtin_amdgcn_sinf(fx);
      row[2 + 4 * i + 1] = (_Float16)__builtin_amdgcn_sinf(fy);
      row[2 + 4 * i + 2] = (_Float16)__builtin_amdgcn_cosf(fx);
      row[2 + 4 * i + 3] = (_Float16)__builtin_amdgcn_cosf(fy);
    }
  }
  __syncthreads();

  // ---- bilinear sampling, 4 channels/iter ----
  {
    const float* gb = grid + (size_t)b * (GH * GW * DM);
#pragma unroll
    for (int it = 0; it < (MT * DM / 4) / TPB; ++it) {
      const int idx = it * TPB + tid;
      const int p = idx >> 5;
      const int c = (idx & 31) * 4;
      const float4 cc4 = cco4[p];
      const int r0 = __float_as_int(cc4.x);
      const int q0 = __float_as_int(cc4.y);
      const float frr = cc4.z, frc = cc4.w;
      const int r1 = min(r0 + 1, GH - 1), q1 = min(q0 + 1, GW - 1);
      const float4 v00 = *(const float4*)(gb + (size_t)(r0 * GW + q0) * DM + c);
      const float4 v01 = *(const float4*)(gb + (size_t)(r0 * GW + q1) * DM + c);
      const float4 v10 = *(const float4*)(gb + (size_t)(r1 * GW + q0) * DM + c);
      const float4 v11 = *(const float4*)(gb + (size_t)(r1 * GW + q1) * DM + c);
      float4 vt, vb, vv;
      vt.x = fmaf(v01.x - v00.x, frc, v00.x);
      vt.y = fmaf(v01.y - v00.y, frc, v00.y);
      vt.z = fmaf(v01.z - v00.z, frc, v00.z);
      vt.w = fmaf(v01.w - v00.w, frc, v00.w);
      vb.x = fmaf(v11.x - v10.x, frc, v10.x);
      vb.y = fmaf(v11.y - v10.y, frc, v10.y);
      vb.z = fmaf(v11.z - v10.z, frc, v10.z);
      vb.w = fmaf(v11.w - v10.w, frc, v10.w);
      vv.x = fmaf(vb.x - vt.x, frr, vt.x);
      vv.y = fmaf(vb.y - vt.y, frr, vt.y);
      vv.z = fmaf(vb.z - vt.z, frr, vt.z);
      vv.w = fmaf(vb.w - vt.w, frr, vt.w);
      const h16x2 lo = __builtin_amdgcn_cvt_pkrtz(vv.x, vv.y);
      const h16x2 hi = __builtin_amdgcn_cvt_pkrtz(vv.z, vv.w);
      *(h16x2*)(act + p * LDK + ENCD + c) = lo;
      *(h16x2*)(act + p * LDK + ENCD + c + 2) = hi;
    }
  }

  // ---- FiLM params: this wave owns 2 n-tiles (cols wc*32 + nt*16 + 0..15) ----
  const int colbase = wc * 32 + (lane & 15);
  float g1[2], btv[2];
#pragma unroll
  for (int nt = 0; nt < 2; ++nt) {
    g1[nt] = film[b * 512 + colbase + nt * 16] + 1.0f;
    btv[nt] = film[b * 512 + MW + colbase + nt * 16];
  }
  __syncthreads();

  const int arow = lane & 15;
  const int kq = (lane >> 4) * 8;

  f32x4 accA[4][2], accB[4][2];

  // fragment loaders
  auto loadB = [&](const _Float16* __restrict__ wl, int kt, f16x8 (&bfr)[2]) {
#pragma unroll
    for (int nt = 0; nt < 2; ++nt)
      bfr[nt] = *(const f16x8*)(wl + ((size_t)((kt * 16 + wc * 2 + nt) * 64 + lane)) * 8);
  };
  auto loadA = [&](int T, int kt, f16x8 (&afr)[4]) {
    const int kof = kt * 32 + kq;
#pragma unroll
    for (int mt = 0; mt < 4; ++mt)
      afr[mt] = *(const f16x8*)(act + (T * 64 + mt * 16 + arow) * LDK + kof);
  };
  auto domfma = [&](f16x8 (&afr)[4], f16x8 (&bfr)[2], f32x4 (&acc)[4][2]) {
#pragma unroll
    for (int mt = 0; mt < 4; ++mt)
#pragma unroll
      for (int nt = 0; nt < 2; ++nt)
        acc[mt][nt] = __builtin_amdgcn_mfma_f32_16x16x32_f16(afr[mt], bfr[nt], acc[mt][nt], 0, 0, 0);
  };

  // one epilogue group (of 8) for tile T: g -> (mt = g>>1, nt = g&1)
  auto epi_group = [&](int g, int T, f32x4 (&acc)[4][2], const float* cbv) {
    const int mt = g >> 1, nt = g & 1;
    const int col = wc * 32 + nt * 16 + (lane & 15);
    const int rowb = T * 64 + mt * 16 + (lane >> 4) * 4;
#pragma unroll
    for (int r = 0; r < 4; ++r) {
      const float v = fmaf(acc[mt][nt][r], g1[nt], cbv[nt]);
      act[(rowb + r) * LDK + col] = (_Float16)gelu_fast(v);
    }
  };

  auto zero = [&](f32x4 (&acc)[4][2]) {
#pragma unroll
    for (int mt = 0; mt < 4; ++mt)
#pragma unroll
      for (int nt = 0; nt < 2; ++nt)
        acc[mt][nt] = (f32x4){0.f, 0.f, 0.f, 0.f};
  };

  float cbv[2];
  auto set_cb = [&](const float* __restrict__ bl) {
#pragma unroll
    for (int nt = 0; nt < 2; ++nt)
      cbv[nt] = fmaf(bl[colbase + nt * 16], g1[nt], btv[nt]);
  };

  // Pipelined segment: Kt ksteps for tile Tk from wl into accK (B-frags loaded
  // 2 ksteps ahead in a rolling 2-buffer), plus (optionally) the 8 epilogue
  // groups of tile Te from accE interleaved one per step.
  auto run_seg = [&](const _Float16* __restrict__ wl, int Kt, int Tk,
                     f32x4 (&accK)[4][2], bool do_epi, int Te,
                     f32x4 (&accE)[4][2]) {
    f16x8 bb[2][2];
    loadB(wl, 0, bb[0]);
    if (Kt > 1) loadB(wl, 1, bb[1]);
#pragma unroll
    for (int s = 0; s < 8; ++s) {
      if (s < Kt) {
        f16x8 afr[4];
        loadA(Tk, s, afr);
        domfma(afr, bb[s & 1], accK);
        if (s + 2 < Kt) loadB(wl, s + 2, bb[s & 1]);  // refill just-freed buffer
      }
      if (do_epi) epi_group(s, Te, accE, cbv);
    }
  };

  const _Float16* wp0 = wpack + (size_t)KT0 * KTU;
  const _Float16* wp1 = wpack + (size_t)KT1 * KTU;
  const _Float16* wp2 = wpack + (size_t)KT2 * KTU;
  const _Float16* wp3 = wpack + (size_t)KT3 * KTU;

  // seg0: K(A,0)
  zero(accA);
  run_seg(wp0, 6, 0, accA, false, 0, accB);
  __syncthreads();

  // seg1: E(A,0) + K(B,0)
  zero(accB); set_cb(b0);
  run_seg(wp0, 6, 1, accB, true, 0, accA);
  __syncthreads();

  // seg2: E(B,0) + K(A,1)
  zero(accA); set_cb(b0);
  run_seg(wp1, 8, 0, accA, true, 1, accB);
  __syncthreads();

  // seg3: E(A,1) + K(B,1)
  zero(accB); set_cb(b1);
  run_seg(wp1, 8, 1, accB, true, 0, accA);
  __syncthreads();

  // seg4: E(B,1) + K(A,2)
  zero(accA); set_cb(b1);
  run_seg(wp2, 8, 0, accA, true, 1, accB);
  __syncthreads();

  // seg5: E(A,2) + K(B,2)
  zero(accB); set_cb(b2);
  run_seg(wp2, 8, 1, accB, true, 0, accA);
  __syncthreads();

  // seg6: E(B,2) + K(A,3)
  zero(accA); set_cb(b2);
  run_seg(wp3, 8, 0, accA, true, 1, accB);
  __syncthreads();

  // seg7: E(A,3) + K(B,3)
  zero(accB); set_cb(b3);
  run_seg(wp3, 8, 1, accB, true, 0, accA);
  __syncthreads();

  // seg8: E(B,3) [all waves] + Kout(tile A) [waves 0..3] + store A
  {
    set_cb(b3);
    const _Float16* wob = wpack + OUT_OFF;
    f32x4 oacc = (f32x4){0.f, 0.f, 0.f, 0.f};
    const int rb = (wc & 3) * 16 + ((wc < 4) ? 0 : 64);  // wave's 16-row slice
#pragma unroll
    for (int s = 0; s < 8; ++s) {
      if (wc < 4) {
        const f16x8 bfr = *(const f16x8*)(wob + (size_t)(s * 64 + lane) * 8);
        const f16x8 afr = *(const f16x8*)(act + (rb + arow) * LDK + s * 32 + kq);
        oacc = __builtin_amdgcn_mfma_f32_16x16x32_f16(afr, bfr, oacc, 0, 0, 0);
      }
      epi_group(s, 1, accB, cbv);
    }
    if (wc < 4) {
      const int col = lane & 15;
      if (col < 3) {
        const float bv = bo[col];
        const int rowb = rb + (lane >> 4) * 4;
#pragma unroll
        for (int r = 0; r < 4; ++r)
          out[((size_t)b * NPTS + n0 + rowb + r) * 3 + col] = tanh_fast(oacc[r] + bv);
      }
    }
    __syncthreads();

    // seg9: Kout(tile B) [waves 4..7] + store B
    if (wc >= 4) {
      f32x4 oacc2 = (f32x4){0.f, 0.f, 0.f, 0.f};
#pragma unroll
      for (int kt = 0; kt < 8; ++kt) {
        const f16x8 bfr = *(const f16x8*)(wob + (size_t)(kt * 64 + lane) * 8);
        const f16x8 afr = *(const f16x8*)(act + (rb + arow) * LDK + kt * 32 + kq);
        oacc2 = __builtin_amdgcn_mfma_f32_16x16x32_f16(afr, bfr, oacc2, 0, 0, 0);
      }
      const int col = lane & 15;
      if (col < 3) {
        const float bv = bo[col];
        const int rowb = rb + (lane >> 4) * 4;
#pragma unroll
        for (int r = 0; r < 4; ++r)
          out[((size_t)b * NPTS + n0 + rowb + r) * 3 + col] = tanh_fast(oacc2[r] + bv);
      }
    }
  }
}

extern "C" void kernel_launch(void* const* d_in, const int* in_sizes, int n_in,
                              void* d_out, int out_size, void* d_ws, size_t ws_size,
                              hipStream_t stream) {
  const float* grid   = (const float*)d_in[0];
  const float* ctx    = (const float*)d_in[1];
  const float* coords = (const float*)d_in[2];
  const float* w0 = (const float*)d_in[3];
  const float* b0 = (const float*)d_in[4];
  const float* w1 = (const float*)d_in[5];
  const float* b1 = (const float*)d_in[6];
  const float* w2 = (const float*)d_in[7];
  const float* b2 = (const float*)d_in[8];
  const float* w3 = (const float*)d_in[9];
  const float* b3 = (const float*)d_in[10];
  const float* wf = (const float*)d_in[11];
  const float* bf = (const float*)d_in[12];
  const float* wo = (const float*)d_in[13];
  const float* bo = (const float*)d_in[14];
  float* out = (float*)d_out;

  float* filmbuf = (float*)d_ws;
  _Float16* wpack = (_Float16*)((char*)d_ws + 8192);

  hipLaunchKernelGGL(prep_kernel, dim3(126), dim3(256), 0, stream,
                     w0, w1, w2, w3, wo, ctx, wf, bf, wpack, filmbuf);
  hipLaunchKernelGGL(decoder_kernel, dim3(NB * (NPTS / MT)), dim3(TPB), 0, stream,
                     grid, coords, b0, b1, b2, b3, bo, filmbuf, wpack, out);
}